// Round 7
// baseline (529.017 us; speedup 1.0000x reference)
//
#include <hip/hip_runtime.h>
#include <math.h>

#define SQ 4096
#define DM 1024
#define NB 4
#define MT (NB*SQ)   // 16384 flattened rows
#define XN ((size_t)MT*DM)
#define NCVT 19456   // (XN + 3*DM*DM)/1024 convert blocks in cvt_all
#define NTILES 528   // causal 128x128 tiles per batch (packed S)
#define STILE 16384  // elems per packed S tile (128*128)
#define NT256 136    // causal 256x256 tiles per batch

typedef __attribute__((ext_vector_type(4))) float f32x4;
typedef __attribute__((ext_vector_type(8))) short s16x8;

__device__ __forceinline__ unsigned short f2bf(float f) {
  union { float f; unsigned int u; } v; v.f = f;
  unsigned int u = v.u;
  u += 0x7fffu + ((u >> 16) & 1u);   // RNE
  return (unsigned short)(u >> 16);
}

__device__ __forceinline__ float bf2f(unsigned short u) {
  union { unsigned int i; float f; } v; v.i = ((unsigned int)u) << 16;
  return v.f;
}

__device__ __forceinline__ void async16(const void* g, void* l) {
  __builtin_amdgcn_global_load_lds(
      (const __attribute__((address_space(1))) unsigned int*)g,
      (__attribute__((address_space(3))) unsigned int*)l, 16, 0, 0);
}

// ---------------- fp32 -> bf16 convert (all 4 inputs) + zero row-sum accumulator ----
__global__ __launch_bounds__(256)
void cvt_all(const float* __restrict__ x, const float* __restrict__ Wq,
             const float* __restrict__ Wk, const float* __restrict__ Wv,
             unsigned short* __restrict__ xb, unsigned short* __restrict__ Wb,
             float* __restrict__ l) {
  if (blockIdx.x >= NCVT) {
    int r = (blockIdx.x - NCVT) * 256 + threadIdx.x;
    l[r] = 0.f;
    return;
  }
  size_t i = ((size_t)blockIdx.x * 256 + threadIdx.x) * 4;
  const float* src; unsigned short* dst;
  if (i < XN) { src = x + i; dst = xb + i; }
  else {
    size_t r = i - XN;
    int w = (int)(r >> 20);                 // DM*DM == 2^20
    size_t off = r & (((size_t)1 << 20) - 1);
    src = (w == 0 ? Wq : (w == 1 ? Wk : Wv)) + off;
    dst = Wb + r;
  }
  float4 f = *(const float4*)src;
  ushort4 o;
  o.x = f2bf(f.x); o.y = f2bf(f.y); o.z = f2bf(f.z); o.w = f2bf(f.w);
  *(ushort4*)dst = o;
}

// ---------------- shared m97-style 128x128xBK64 K-loop (proj only) ----------------
// NOTE (r0-r3): 8-phase scheduling attempts all land at ~34% MfmaUtil like this
// 2-phase body. Tile SIZE (not schedule) is the lever for staging-BW-bound passes.
template<int LDA, int LDB>
__device__ __forceinline__ void gemm_tile_body(
    const unsigned short* __restrict__ A, const unsigned short* __restrict__ B,
    unsigned short* As, unsigned short* Bs,
    int m0, int n0, int kext, f32x4 acc[4][4]) {
  const int tid = threadIdx.x, lane = tid & 63, wid = tid >> 6;
  const int quad = lane >> 4, l15 = lane & 15;
  const int wm = wid & 1, wn = wid >> 1;

  const int rbase = wid * 32 + (lane >> 3);
  const int kg8   = ((lane & 7) ^ (lane >> 3)) * 8;
  const unsigned short* Ab = A + (size_t)(m0 + rbase) * LDA + kg8;
  const unsigned short* Bb = B + (size_t)(n0 + rbase) * LDB + kg8;
  unsigned short* Asl = As + (wid * 256 + lane) * 8;
  unsigned short* Bsl = Bs + (wid * 256 + lane) * 8;
  const int xorq = (quad ^ (l15 & 7)) * 8;
  const int am = (wm * 64 + l15) * 64 + xorq;
  const int bn = (wn * 64 + l15) * 64 + xorq;

  for (int k0 = 0; k0 < kext; k0 += 64) {
#pragma unroll
    for (int c = 0; c < 4; c++) {
      async16(Ab + (size_t)c * 8 * LDA + k0, Asl + c * 512);
      async16(Bb + (size_t)c * 8 * LDB + k0, Bsl + c * 512);
    }
    asm volatile("s_waitcnt vmcnt(0)" ::: "memory");
    __syncthreads();
#pragma unroll
    for (int ks = 0; ks < 2; ks++) {
      const int ax = am ^ (ks * 32), bx = bn ^ (ks * 32);
      s16x8 af[4], bfr[4];
#pragma unroll
      for (int t = 0; t < 4; t++) {
        af[t]  = *(const s16x8*)(As + ax + t * 1024);
        bfr[t] = *(const s16x8*)(Bs + bx + t * 1024);
      }
#pragma unroll
      for (int tm = 0; tm < 4; tm++)
#pragma unroll
        for (int tn = 0; tn < 4; tn++)
          acc[tm][tn] = __builtin_amdgcn_mfma_f32_16x16x32_bf16(af[tm], bfr[tn], acc[tm][tn], 0, 0, 0);
    }
    __syncthreads();
  }
}

// ---------------- QKV projection, single dispatch: Q,K (rope) + V (direct-Vt) ----------
__global__ __launch_bounds__(256, 3)
void proj_all(const unsigned short* __restrict__ A,
              const unsigned short* __restrict__ Wb,
              unsigned short* __restrict__ QKV) {
  __shared__ unsigned short As[128 * 64];
  __shared__ unsigned short Bs[128 * 64];
  const int lane = threadIdx.x & 63, wid = threadIdx.x >> 6;
  const int quad = lane >> 4, l15 = lane & 15;
  const int wm = wid & 1, wn = wid >> 1;
  const int mat = blockIdx.y >> 3;                 // 0,1 -> rope; 2 -> V
  const int m0 = blockIdx.x * 128, n0 = (blockIdx.y & 7) * 128;

  f32x4 zero = {0.f, 0.f, 0.f, 0.f};
  f32x4 acc[4][4];
#pragma unroll
  for (int i = 0; i < 4; i++)
#pragma unroll
    for (int j = 0; j < 4; j++) acc[i][j] = zero;

  gemm_tile_body<DM, DM>(A, Wb + (size_t)mat * DM * DM, As, Bs, m0, n0, DM, acc);

  if (mat < 2) {
    unsigned short* C = QKV + (size_t)mat * XN;
    const bool ev = (lane & 1) == 0;
#pragma unroll
    for (int tm = 0; tm < 4; tm++) {
      int rowb = m0 + wm * 64 + tm * 16 + quad * 4;
#pragma unroll
      for (int tn = 0; tn < 4; tn++) {
        int col = n0 + wn * 64 + tn * 16 + l15;
        f32x4 v = acc[tm][tn];
        float invr = exp2f(-(float)(col & ~1) * (13.287712379549449f / 1024.0f)) * 0.15915494309f;
#pragma unroll
        for (int g = 0; g < 4; g++) {
          int row = rowb + g;
          float rev = (float)(row & (SQ - 1)) * invr;
          rev -= floorf(rev);
          float sn, cs;
          __sincosf(rev * 6.283185307179586f, &sn, &cs);
          float part = __shfl_xor(v[g], 1);
          float e = ev ? v[g] : part;
          float o = ev ? part : v[g];
          float re = e * cs - o * sn;
          float ro = e * sn + o * cs;
          if (ev) {
            unsigned int pk = (unsigned int)f2bf(re) | ((unsigned int)f2bf(ro) << 16);
            *(unsigned int*)(C + (size_t)row * DM + col) = pk;
          }
        }
      }
    }
  } else {
    unsigned short* Vt = QKV + (size_t)2 * XN;     // [b][d][s]
#pragma unroll
    for (int tm = 0; tm < 4; tm++) {
      int rowb = m0 + wm * 64 + tm * 16 + quad * 4;
      int b = rowb >> 12;
      int s = rowb & (SQ - 1);                     // 4 rows, same batch, s..s+3
#pragma unroll
      for (int tn = 0; tn < 4; tn++) {
        int col = n0 + wn * 64 + tn * 16 + l15;
        f32x4 v = acc[tm][tn];
        ushort4 o;
        o.x = f2bf(v[0]); o.y = f2bf(v[1]); o.z = f2bf(v[2]); o.w = f2bf(v[3]);
        *(ushort4*)(Vt + (size_t)b * DM * SQ + (size_t)col * SQ + s) = o;
      }
    }
  }
}

// ---------------- pass1: P' = exp(QK^T/32), 256^2 tiles, 512 threads, packed-S out ----
// 544 blocks: b = bx/136, t = bx%136 (triangular 256-tile id, nt<=mt). BM=BN=256
// halves staged bytes vs 128^2 (staging-BW-bound pass; intensity 21 flop/B).
// 8 waves as (wm = wid>>2: 128-row half, wn = wid&3: 64-col quarter); acc[8][4].
// Epilogue maps each 128-quadrant into the packed triangular S (the diagonal
// 256-tile's upper-right 128-quadrant is skipped — exp->0, not stored, not read).
__global__ __launch_bounds__(512, 2)
void qk256(const unsigned short* __restrict__ Q, const unsigned short* __restrict__ K,
           unsigned short* __restrict__ S, float* __restrict__ l) {
  __shared__ unsigned short As[256 * 64];
  __shared__ unsigned short Bs[256 * 64];
  const int tid = threadIdx.x, lane = tid & 63, wid = tid >> 6;
  const int quad = lane >> 4, l15 = lane & 15;
  const int wm = wid >> 2, wn = wid & 3;

  const int b = blockIdx.x / NT256;
  int t = blockIdx.x - b * NT256;
  int mt = (int)((sqrtf(8.f * (float)t + 1.f) - 1.f) * 0.5f);
  while ((mt + 1) * (mt + 2) / 2 <= t) ++mt;
  while (mt * (mt + 1) / 2 > t) --mt;
  int nt = t - mt * (mt + 1) / 2;

  const unsigned short* Qg = Q + (size_t)b * SQ * DM;
  const unsigned short* Kg = K + (size_t)b * SQ * DM;
  unsigned short* Sg = S + (size_t)b * NTILES * STILE;
  float* lrow = l + b * SQ;

  const int rstage = wid * 16 + (lane >> 3);       // 0..127 (with +8 pair)
  const int kg8 = ((lane & 7) ^ (lane >> 3)) * 8;
  const unsigned short* Ab = Qg + (size_t)(mt * 256 + rstage) * DM + kg8;
  const unsigned short* Bb = Kg + (size_t)(nt * 256 + rstage) * DM + kg8;
  unsigned short* Asl = As + wid * 1024 + lane * 8;
  unsigned short* Bsl = Bs + wid * 1024 + lane * 8;
  const int xorq = (quad ^ (l15 & 7)) * 8;
  const int am = (wm * 128 + l15) * 64 + xorq;
  const int bn = (wn * 64 + l15) * 64 + xorq;

  f32x4 zero = {0.f, 0.f, 0.f, 0.f};
  f32x4 acc[8][4];
#pragma unroll
  for (int i = 0; i < 8; i++)
#pragma unroll
    for (int j = 0; j < 4; j++) acc[i][j] = zero;

  for (int k0 = 0; k0 < DM; k0 += 64) {
    async16(Ab + k0, Asl);
    async16(Ab + (size_t)8 * DM + k0, Asl + 512);
    async16(Ab + (size_t)128 * DM + k0, Asl + 8192);
    async16(Ab + (size_t)136 * DM + k0, Asl + 8704);
    async16(Bb + k0, Bsl);
    async16(Bb + (size_t)8 * DM + k0, Bsl + 512);
    async16(Bb + (size_t)128 * DM + k0, Bsl + 8192);
    async16(Bb + (size_t)136 * DM + k0, Bsl + 8704);
    asm volatile("s_waitcnt vmcnt(0)" ::: "memory");
    __syncthreads();
#pragma unroll
    for (int ks = 0; ks < 2; ks++) {
      const int ax = am ^ (ks * 32), bx = bn ^ (ks * 32);
      s16x8 af[8], bfr[4];
#pragma unroll
      for (int u = 0; u < 8; u++) af[u] = *(const s16x8*)(As + ax + u * 1024);
#pragma unroll
      for (int u = 0; u < 4; u++) bfr[u] = *(const s16x8*)(Bs + bx + u * 1024);
#pragma unroll
      for (int tm = 0; tm < 8; tm++)
#pragma unroll
        for (int tn = 0; tn < 4; tn++)
          acc[tm][tn] = __builtin_amdgcn_mfma_f32_16x16x32_bf16(af[tm], bfr[tn], acc[tm][tn], 0, 0, 0);
    }
    __syncthreads();
  }

  const bool ev = (lane & 1) == 0;
#pragma unroll
  for (int tm = 0; tm < 8; tm++) {
    int lr = wm * 128 + tm * 16 + quad * 4;         // tile-local row (0..255)
    int grow = mt * 256 + lr;
    int r128 = mt * 2 + (lr >> 7);
    float rsum[4] = {0.f, 0.f, 0.f, 0.f};
#pragma unroll
    for (int tn = 0; tn < 4; tn++) {
      int lc = wn * 64 + tn * 16 + l15;             // tile-local col (0..255)
      int gcol = nt * 256 + lc;
      int c128 = nt * 2 + (lc >> 7);
      const bool store = (c128 <= r128);
      unsigned short* St = Sg + ((size_t)(r128 * (r128 + 1) / 2 + c128) << 14);
      f32x4 v = acc[tm][tn];
#pragma unroll
      for (int g = 0; g < 4; g++) {
        float p = (gcol <= grow + g) ? __expf(v[g] * 0.03125f) : 0.f;
        rsum[g] += p;
        float part = __shfl_xor(p, 1);
        if (ev && store) {
          unsigned int pk = (unsigned int)f2bf(p) | ((unsigned int)f2bf(part) << 16);
          *(unsigned int*)(St + (size_t)((lr & 127) + g) * 128 + (lc & 127)) = pk;
        }
      }
    }
#pragma unroll
    for (int g = 0; g < 4; g++) {
      float s = rsum[g];
#pragma unroll
      for (int o = 8; o >= 1; o >>= 1) s += __shfl_xor(s, o);
      if (l15 == 0) atomicAdd(&lrow[grow + g], s);
    }
  }
}

// ---------------- pass2: O = (P' @ V)/l, 256m x 256n tiles, packed-P A-operand ----
// 256 blocks = 16 mt x 4 nt x 4 b (1/CU); mt = 15-q (longest first). A row-half0
// (r128=2mt) reads packed tiles tri(2mt)+j for j<=2mt; half1 (r128=2mt+1) for
// j<=2mt+1 — the final j is a half1-only step (wm=0 waves skip MFMA, uniform).
// Staged bytes halved vs the 128x256 version (the BW-bound wall).
__global__ __launch_bounds__(512, 2)
void pv256(const unsigned short* __restrict__ P, const unsigned short* __restrict__ Vt,
           const float* __restrict__ l, float* __restrict__ O) {
  __shared__ unsigned short As[256 * 64];
  __shared__ unsigned short Bs[256 * 64];
  const int tid = threadIdx.x, lane = tid & 63, wid = tid >> 6;
  const int quad = lane >> 4, l15 = lane & 15;
  const int wm = wid >> 2, wn = wid & 3;

  const int q = blockIdx.x >> 4;                   // 0..15
  const int sub = blockIdx.x & 15;
  const int nt = sub >> 2, b = sub & 3;
  const int mt = 15 - q;                           // longest-K first

  const unsigned short* Pg = P + (size_t)b * NTILES * STILE;
  const unsigned short* Vg = Vt + (size_t)b * DM * SQ;
  const float* lg = l + b * SQ;
  float* Og = O + (size_t)b * SQ * DM;
  const int tb0 = (2 * mt) * (2 * mt + 1) / 2;     // tri base, row-half0
  const int tb1 = (2 * mt + 1) * (2 * mt + 2) / 2; // tri base, row-half1
  const int n0 = nt * 256;

  const int rstage = wid * 16 + (lane >> 3);
  const int kg8 = ((lane & 7) ^ (lane >> 3)) * 8;
  const unsigned short* Bb = Vg + (size_t)(n0 + rstage) * SQ + kg8;
  unsigned short* Asl = As + wid * 1024 + lane * 8;
  unsigned short* Bsl = Bs + wid * 1024 + lane * 8;
  const int xorq = (quad ^ (l15 & 7)) * 8;
  const int am = (wm * 128 + l15) * 64 + xorq;
  const int bn = (wn * 64 + l15) * 64 + xorq;

  f32x4 zero = {0.f, 0.f, 0.f, 0.f};
  f32x4 acc[8][4];
#pragma unroll
  for (int i = 0; i < 8; i++)
#pragma unroll
    for (int j = 0; j < 4; j++) acc[i][j] = zero;

  const int jmax = 2 * mt + 1;                     // final j: half1 only
  for (int j = 0; j <= jmax; ++j) {
    const unsigned short* At0 = Pg + ((size_t)(tb0 + j) << 14) + kg8;
    const unsigned short* At1 = Pg + ((size_t)(tb1 + j) << 14) + kg8;
#pragma unroll 1
    for (int ks2 = 0; ks2 < 2; ks2++) {
      const int ko = ks2 * 64;
      if (j < jmax) {
        async16(At0 + (size_t)rstage * 128 + ko, Asl);
        async16(At0 + (size_t)(rstage + 8) * 128 + ko, Asl + 512);
      }
      async16(At1 + (size_t)rstage * 128 + ko, Asl + 8192);
      async16(At1 + (size_t)(rstage + 8) * 128 + ko, Asl + 8704);
      const int k0 = j * 128 + ko;
      async16(Bb + k0, Bsl);
      async16(Bb + (size_t)8 * SQ + k0, Bsl + 512);
      async16(Bb + (size_t)128 * SQ + k0, Bsl + 8192);
      async16(Bb + (size_t)136 * SQ + k0, Bsl + 8704);
      asm volatile("s_waitcnt vmcnt(0)" ::: "memory");
      __syncthreads();
      if (j < jmax || wm == 1) {
#pragma unroll
        for (int ks = 0; ks < 2; ks++) {
          const int ax = am ^ (ks * 32), bx = bn ^ (ks * 32);
          s16x8 af[8], bfr[4];
#pragma unroll
          for (int u = 0; u < 8; u++) af[u] = *(const s16x8*)(As + ax + u * 1024);
#pragma unroll
          for (int u = 0; u < 4; u++) bfr[u] = *(const s16x8*)(Bs + bx + u * 1024);
#pragma unroll
          for (int tm = 0; tm < 8; tm++)
#pragma unroll
            for (int tn = 0; tn < 4; tn++)
              acc[tm][tn] = __builtin_amdgcn_mfma_f32_16x16x32_bf16(af[tm], bfr[tn], acc[tm][tn], 0, 0, 0);
        }
      }
      __syncthreads();
    }
  }

  const bool ev = (lane & 1) == 0;
#pragma unroll
  for (int tm = 0; tm < 8; tm++) {
    int grow = mt * 256 + wm * 128 + tm * 16 + quad * 4;
    float rl[4];
#pragma unroll
    for (int g = 0; g < 4; g++) rl[g] = 1.0f / lg[grow + g];
#pragma unroll
    for (int tn = 0; tn < 4; tn++) {
      int col = n0 + wn * 64 + tn * 16 + l15;
      f32x4 v = acc[tm][tn];
#pragma unroll
      for (int g = 0; g < 4; g++) {
        float val = v[g] * rl[g];
        float part = __shfl_xor(val, 1);
        if (ev) {
          float2 st; st.x = val; st.y = part;
          *(float2*)(Og + (size_t)(grow + g) * DM + col) = st;
        }
      }
    }
  }
}

extern "C" void kernel_launch(void* const* d_in, const int* in_sizes, int n_in,
                              void* d_out, int out_size, void* d_ws, size_t ws_size,
                              hipStream_t stream) {
  const float* x  = (const float*)d_in[0];
  const float* Wq = (const float*)d_in[1];
  const float* Wk = (const float*)d_in[2];
  const float* Wv = (const float*)d_in[3];
  float* out = (float*)d_out;

  // workspace layout (bf16 elems). QKV first; packed S (69.2 MB) overlays the
  // dead-after-proj xb+Wb region. Peak 169.9 MB <= proven ws floor (174.1 MB).
  unsigned short* Qb  = (unsigned short*)d_ws;
  unsigned short* xb  = Qb + 3 * XN;
  unsigned short* Wb  = xb + XN;
  unsigned short* Sb  = xb;                              // overlay
  float* lfull = (float*)(Sb + (size_t)NB * NTILES * STILE);

  (void)ws_size; (void)in_sizes; (void)n_in; (void)out_size;

  cvt_all<<<NCVT + 64, 256, 0, stream>>>(x, Wq, Wk, Wv, xb, Wb, lfull);

  proj_all<<<dim3(MT / 128, 24), 256, 0, stream>>>(xb, Wb, Qb);

  qk256<<<NB * NT256, 512, 0, stream>>>(Qb, Qb + XN, Sb, lfull);

  pv256<<<256, 512, 0, stream>>>(Sb, Qb + 2 * XN, lfull, out);
}

// Round 8
// 417.441 us; speedup vs baseline: 1.2673x; 1.2673x over previous
//
#include <hip/hip_runtime.h>
#include <math.h>

#define SQ 4096
#define DM 1024
#define NB 4
#define MT (NB*SQ)   // 16384 flattened rows
#define XN ((size_t)MT*DM)
#define NCVT 19456   // (XN + 3*DM*DM)/1024 convert blocks in cvt_all
#define NTILES 528   // causal 128x128 tiles per batch (packed S)
#define STILE 16384  // elems per packed S tile (128*128)

typedef __attribute__((ext_vector_type(4))) float f32x4;
typedef __attribute__((ext_vector_type(8))) short s16x8;

__device__ __forceinline__ unsigned short f2bf(float f) {
  union { float f; unsigned int u; } v; v.f = f;
  unsigned int u = v.u;
  u += 0x7fffu + ((u >> 16) & 1u);   // RNE
  return (unsigned short)(u >> 16);
}

__device__ __forceinline__ float bf2f(unsigned short u) {
  union { unsigned int i; float f; } v; v.i = ((unsigned int)u) << 16;
  return v.f;
}

__device__ __forceinline__ void async16(const void* g, void* l) {
  __builtin_amdgcn_global_load_lds(
      (const __attribute__((address_space(1))) unsigned int*)g,
      (__attribute__((address_space(3))) unsigned int*)l, 16, 0, 0);
}

// ---------------- fp32 -> bf16 convert (all 4 inputs) + zero row-sum accumulator ----
__global__ __launch_bounds__(256)
void cvt_all(const float* __restrict__ x, const float* __restrict__ Wq,
             const float* __restrict__ Wk, const float* __restrict__ Wv,
             unsigned short* __restrict__ xb, unsigned short* __restrict__ Wb,
             float* __restrict__ l) {
  if (blockIdx.x >= NCVT) {
    int r = (blockIdx.x - NCVT) * 256 + threadIdx.x;
    l[r] = 0.f;
    return;
  }
  size_t i = ((size_t)blockIdx.x * 256 + threadIdx.x) * 4;
  const float* src; unsigned short* dst;
  if (i < XN) { src = x + i; dst = xb + i; }
  else {
    size_t r = i - XN;
    int w = (int)(r >> 20);                 // DM*DM == 2^20
    size_t off = r & (((size_t)1 << 20) - 1);
    src = (w == 0 ? Wq : (w == 1 ? Wk : Wv)) + off;
    dst = Wb + r;
  }
  float4 f = *(const float4*)src;
  ushort4 o;
  o.x = f2bf(f.x); o.y = f2bf(f.y); o.z = f2bf(f.z); o.w = f2bf(f.w);
  *(ushort4*)dst = o;
}

// ---------------- shared m97-style 128x128xBK64 K-loop, hoisted addressing ----------------
// NOTE (r0-r3): 8-phase / 256^2 variants tried three times (132.5 / 127.0 / 153.5 us)
// — all regress or tie vs this 128^2 3-blocks/CU body. The 2-phase structure's 35%
// MfmaUtil comes from cross-BLOCK overlap (3/CU); geometry that drops blocks/CU loses
// it (r6: 256^2 -> 19%). Do not re-attempt without a wave-stagger mechanism.
template<int LDA, int LDB>
__device__ __forceinline__ void gemm_tile_body(
    const unsigned short* __restrict__ A, const unsigned short* __restrict__ B,
    unsigned short* As, unsigned short* Bs,
    int m0, int n0, int kext, f32x4 acc[4][4]) {
  const int tid = threadIdx.x, lane = tid & 63, wid = tid >> 6;
  const int quad = lane >> 4, l15 = lane & 15;
  const int wm = wid & 1, wn = wid >> 1;

  const int rbase = wid * 32 + (lane >> 3);
  const int kg8   = ((lane & 7) ^ (lane >> 3)) * 8;
  const unsigned short* Ab = A + (size_t)(m0 + rbase) * LDA + kg8;
  const unsigned short* Bb = B + (size_t)(n0 + rbase) * LDB + kg8;
  unsigned short* Asl = As + (wid * 256 + lane) * 8;
  unsigned short* Bsl = Bs + (wid * 256 + lane) * 8;
  const int xorq = (quad ^ (l15 & 7)) * 8;
  const int am = (wm * 64 + l15) * 64 + xorq;
  const int bn = (wn * 64 + l15) * 64 + xorq;

  for (int k0 = 0; k0 < kext; k0 += 64) {
#pragma unroll
    for (int c = 0; c < 4; c++) {
      async16(Ab + (size_t)c * 8 * LDA + k0, Asl + c * 512);
      async16(Bb + (size_t)c * 8 * LDB + k0, Bsl + c * 512);
    }
    asm volatile("s_waitcnt vmcnt(0)" ::: "memory");
    __syncthreads();
#pragma unroll
    for (int ks = 0; ks < 2; ks++) {
      const int ax = am ^ (ks * 32), bx = bn ^ (ks * 32);
      s16x8 af[4], bfr[4];
#pragma unroll
      for (int t = 0; t < 4; t++) {
        af[t]  = *(const s16x8*)(As + ax + t * 1024);
        bfr[t] = *(const s16x8*)(Bs + bx + t * 1024);
      }
#pragma unroll
      for (int tm = 0; tm < 4; tm++)
#pragma unroll
        for (int tn = 0; tn < 4; tn++)
          acc[tm][tn] = __builtin_amdgcn_mfma_f32_16x16x32_bf16(af[tm], bfr[tn], acc[tm][tn], 0, 0, 0);
    }
    __syncthreads();
  }
}

// ---------------- QKV projection, single dispatch: Q,K (rope) + V (direct-Vt) ----------
// grid (128, 24): by>>3 = mat; n0 = (by&7)*128. x-fastest: consecutive blocks share
// the W slab (L2-resident -> proj runs at the structural ceiling). Do NOT swizzle this
// grid (earlier %8 swizzle regressed FETCH 136->323 MB).
__global__ __launch_bounds__(256, 3)
void proj_all(const unsigned short* __restrict__ A,
              const unsigned short* __restrict__ Wb,
              unsigned short* __restrict__ QKV) {
  __shared__ unsigned short As[128 * 64];
  __shared__ unsigned short Bs[128 * 64];
  const int lane = threadIdx.x & 63, wid = threadIdx.x >> 6;
  const int quad = lane >> 4, l15 = lane & 15;
  const int wm = wid & 1, wn = wid >> 1;
  const int mat = blockIdx.y >> 3;                 // 0,1 -> rope; 2 -> V
  const int m0 = blockIdx.x * 128, n0 = (blockIdx.y & 7) * 128;

  f32x4 zero = {0.f, 0.f, 0.f, 0.f};
  f32x4 acc[4][4];
#pragma unroll
  for (int i = 0; i < 4; i++)
#pragma unroll
    for (int j = 0; j < 4; j++) acc[i][j] = zero;

  gemm_tile_body<DM, DM>(A, Wb + (size_t)mat * DM * DM, As, Bs, m0, n0, DM, acc);

  if (mat < 2) {
    unsigned short* C = QKV + (size_t)mat * XN;
    const bool ev = (lane & 1) == 0;
#pragma unroll
    for (int tm = 0; tm < 4; tm++) {
      int rowb = m0 + wm * 64 + tm * 16 + quad * 4;
#pragma unroll
      for (int tn = 0; tn < 4; tn++) {
        int col = n0 + wn * 64 + tn * 16 + l15;
        f32x4 v = acc[tm][tn];
        float invr = exp2f(-(float)(col & ~1) * (13.287712379549449f / 1024.0f)) * 0.15915494309f;
#pragma unroll
        for (int g = 0; g < 4; g++) {
          int row = rowb + g;
          float rev = (float)(row & (SQ - 1)) * invr;
          rev -= floorf(rev);
          float sn, cs;
          __sincosf(rev * 6.283185307179586f, &sn, &cs);
          float part = __shfl_xor(v[g], 1);
          float e = ev ? v[g] : part;
          float o = ev ? part : v[g];
          float re = e * cs - o * sn;
          float ro = e * sn + o * cs;
          if (ev) {
            unsigned int pk = (unsigned int)f2bf(re) | ((unsigned int)f2bf(ro) << 16);
            *(unsigned int*)(C + (size_t)row * DM + col) = pk;
          }
        }
      }
    }
  } else {
    unsigned short* Vt = QKV + (size_t)2 * XN;     // [b][d][s]
#pragma unroll
    for (int tm = 0; tm < 4; tm++) {
      int rowb = m0 + wm * 64 + tm * 16 + quad * 4;
      int b = rowb >> 12;
      int s = rowb & (SQ - 1);                     // 4 rows, same batch, s..s+3
#pragma unroll
      for (int tn = 0; tn < 4; tn++) {
        int col = n0 + wn * 64 + tn * 16 + l15;
        f32x4 v = acc[tm][tn];
        ushort4 o;
        o.x = f2bf(v[0]); o.y = f2bf(v[1]); o.z = f2bf(v[2]); o.w = f2bf(v[3]);
        *(ushort4*)(Vt + (size_t)b * DM * SQ + (size_t)col * SQ + s) = o;
      }
    }
  }
}

// ---------------- pass1: P' = exp(QK^T/32), causal, PACKED-tile bf16 out ----------
// 2112 blocks, XCD-chunked swizzle (2112 = 8 x 264, bijective): XCD x gets the
// contiguous triangular-id chunk [264x, 264x+264). Its ~96 concurrent blocks share
// a few Q row-slabs (~3 MB, fits 4 MB per-XCD L2) and march K in lockstep ->
// staging L2-amplified instead of L3-fed (qk blocks ran ~1.75x proj's per-block
// cost on an identical GEMM body; operand locality is the difference).
__global__ __launch_bounds__(256, 3)
void qk_gemm(const unsigned short* __restrict__ Q, const unsigned short* __restrict__ K,
             unsigned short* __restrict__ S, float* __restrict__ l) {
  __shared__ unsigned short As[128 * 64];
  __shared__ unsigned short Bs[128 * 64];
  const int lane = threadIdx.x & 63, wid = threadIdx.x >> 6;
  const int quad = lane >> 4, l15 = lane & 15;
  const int wm = wid & 1, wn = wid >> 1;

  const int logical = (blockIdx.x & 7) * 264 + (blockIdx.x >> 3);
  const int b = logical / NTILES;
  int t = logical - b * NTILES;
  int mt = (int)((sqrtf(8.f * (float)t + 1.f) - 1.f) * 0.5f);
  while ((mt + 1) * (mt + 2) / 2 <= t) ++mt;
  while (mt * (mt + 1) / 2 > t) --mt;
  int nt = t - mt * (mt + 1) / 2;

  const unsigned short* Qg = Q + (size_t)b * SQ * DM;
  const unsigned short* Kg = K + (size_t)b * SQ * DM;
  unsigned short* Sg = S + (size_t)b * NTILES * STILE + ((size_t)t << 14);
  float* lrow = l + b * SQ;

  f32x4 zero = {0.f, 0.f, 0.f, 0.f};
  f32x4 acc[4][4];
#pragma unroll
  for (int i = 0; i < 4; i++)
#pragma unroll
    for (int j = 0; j < 4; j++) acc[i][j] = zero;

  gemm_tile_body<DM, DM>(Qg, Kg, As, Bs, mt * 128, nt * 128, DM, acc);

  const bool ev = (lane & 1) == 0;
#pragma unroll
  for (int tm = 0; tm < 4; tm++) {
    int lr = wm * 64 + tm * 16 + quad * 4;          // tile-local row
    int grow = mt * 128 + lr;
    float rsum[4] = {0.f, 0.f, 0.f, 0.f};
#pragma unroll
    for (int tn = 0; tn < 4; tn++) {
      int lc = wn * 64 + tn * 16 + l15;             // tile-local col
      int gcol = nt * 128 + lc;
      f32x4 v = acc[tm][tn];
#pragma unroll
      for (int g = 0; g < 4; g++) {
        float p = (gcol <= grow + g) ? __expf(v[g] * 0.03125f) : 0.f;
        rsum[g] += p;
        float part = __shfl_xor(p, 1);
        if (ev) {
          unsigned int pk = (unsigned int)f2bf(p) | ((unsigned int)f2bf(part) << 16);
          *(unsigned int*)(Sg + (size_t)(lr + g) * 128 + lc) = pk;
        }
      }
    }
#pragma unroll
    for (int g = 0; g < 4; g++) {
      float s = rsum[g];
#pragma unroll
      for (int o = 8; o >= 1; o >>= 1) s += __shfl_xor(s, o);
      if (l15 == 0) atomicAdd(&lrow[grow + g], s);
    }
  }
}

// ---------------- pass2: O = (P' @ V)/l, uniform complementary-pair blocks ----------
// 512 blocks (= 2/CU exactly), logical id = ((b*16 + p)*8 + nt): block computes
// m-tiles mt=p AND mt=31-p at n-tile nt -> constant 66 k-steps per block, zero tail.
// XCD swizzle (512 = 8 x 64): XCD x gets 8 consecutive p-groups of one batch; the
// 8 nt-blocks of each (b,p) run in lockstep reading the SAME packed-P tile at the
// same k-step -> P staging (the dominant stream) served once per XCD from L2.
__global__ __launch_bounds__(256, 3)
void pv_pair(const unsigned short* __restrict__ P, const unsigned short* __restrict__ Vt,
             const float* __restrict__ l, float* __restrict__ O) {
  __shared__ unsigned short As[128 * 64];
  __shared__ unsigned short Bs[128 * 64];
  const int lane = threadIdx.x & 63, wid = threadIdx.x >> 6;
  const int quad = lane >> 4, l15 = lane & 15;
  const int wm = wid & 1, wn = wid >> 1;

  const int logical = (blockIdx.x & 7) * 64 + (blockIdx.x >> 3);
  const int b = logical >> 7;                      // 128 logical ids per batch
  const int p = (logical >> 3) & 15;
  const int nt = logical & 7;

  const unsigned short* Pg = P + (size_t)b * NTILES * STILE;
  const unsigned short* Vg = Vt + (size_t)b * DM * SQ;
  const float* lg = l + b * SQ;
  float* Og = O + (size_t)b * SQ * DM;
  const int n0 = nt * 128;

  const int rbase = wid * 32 + (lane >> 3);
  const int kg8 = ((lane & 7) ^ (lane >> 3)) * 8;
  const unsigned short* Bb = Vg + (size_t)(n0 + rbase) * SQ + kg8;
  unsigned short* Asl = As + (wid * 256 + lane) * 8;
  unsigned short* Bsl = Bs + (wid * 256 + lane) * 8;
  const int xorq = (quad ^ (l15 & 7)) * 8;
  const int am = (wm * 64 + l15) * 64 + xorq;
  const int bn = (wn * 64 + l15) * 64 + xorq;
  const bool ev = (lane & 1) == 0;

  f32x4 zero = {0.f, 0.f, 0.f, 0.f};
#pragma unroll 1
  for (int half = 0; half < 2; half++) {
    const int mt = half ? (31 - p) : p;
    const int tb = mt * (mt + 1) / 2;              // packed tri base of row mt
    f32x4 acc[4][4];
#pragma unroll
    for (int i = 0; i < 4; i++)
#pragma unroll
      for (int j = 0; j < 4; j++) acc[i][j] = zero;

    for (int j = 0; j <= mt; ++j) {
      const unsigned short* At = Pg + ((size_t)(tb + j) << 14) + kg8;
      const int kbase = j * 128;
#pragma unroll 1
      for (int ks2 = 0; ks2 < 2; ks2++) {
        const int ko = ks2 * 64;
#pragma unroll
        for (int c = 0; c < 4; c++) {
          async16(At + (size_t)(rbase + 8 * c) * 128 + ko, Asl + c * 512);
          async16(Bb + (size_t)c * 8 * SQ + kbase + ko, Bsl + c * 512);
        }
        asm volatile("s_waitcnt vmcnt(0)" ::: "memory");
        __syncthreads();
#pragma unroll
        for (int ks = 0; ks < 2; ks++) {
          const int ax = am ^ (ks * 32), bx = bn ^ (ks * 32);
          s16x8 af[4], bfr[4];
#pragma unroll
          for (int u = 0; u < 4; u++) {
            af[u]  = *(const s16x8*)(As + ax + u * 1024);
            bfr[u] = *(const s16x8*)(Bs + bx + u * 1024);
          }
#pragma unroll
          for (int tm = 0; tm < 4; tm++)
#pragma unroll
            for (int tn = 0; tn < 4; tn++)
              acc[tm][tn] = __builtin_amdgcn_mfma_f32_16x16x32_bf16(af[tm], bfr[tn], acc[tm][tn], 0, 0, 0);
        }
        __syncthreads();
      }
    }

#pragma unroll
    for (int tm = 0; tm < 4; tm++) {
      int grow = mt * 128 + wm * 64 + tm * 16 + quad * 4;
      float rl[4];
#pragma unroll
      for (int g = 0; g < 4; g++) rl[g] = 1.0f / lg[grow + g];
#pragma unroll
      for (int tn = 0; tn < 4; tn++) {
        int col = n0 + wn * 64 + tn * 16 + l15;
        f32x4 v = acc[tm][tn];
#pragma unroll
        for (int g = 0; g < 4; g++) {
          float val = v[g] * rl[g];
          float part = __shfl_xor(val, 1);
          if (ev) {
            float2 st; st.x = val; st.y = part;
            *(float2*)(Og + (size_t)(grow + g) * DM + col) = st;
          }
        }
      }
    }
  }
}

extern "C" void kernel_launch(void* const* d_in, const int* in_sizes, int n_in,
                              void* d_out, int out_size, void* d_ws, size_t ws_size,
                              hipStream_t stream) {
  const float* x  = (const float*)d_in[0];
  const float* Wq = (const float*)d_in[1];
  const float* Wk = (const float*)d_in[2];
  const float* Wv = (const float*)d_in[3];
  float* out = (float*)d_out;

  // workspace layout (bf16 elems). QKV first; packed S (69.2 MB) overlays the
  // dead-after-proj xb+Wb region. Peak 169.9 MB <= proven ws floor (174.1 MB).
  unsigned short* Qb  = (unsigned short*)d_ws;
  unsigned short* xb  = Qb + 3 * XN;
  unsigned short* Wb  = xb + XN;
  unsigned short* Sb  = xb;                              // overlay
  float* lfull = (float*)(Sb + (size_t)NB * NTILES * STILE);

  (void)ws_size; (void)in_sizes; (void)n_in; (void)out_size;

  cvt_all<<<NCVT + 64, 256, 0, stream>>>(x, Wq, Wk, Wv, xb, Wb, lfull);

  proj_all<<<dim3(MT / 128, 24), 256, 0, stream>>>(xb, Wb, Qb);

  qk_gemm<<<NB * NTILES, 256, 0, stream>>>(Qb, Qb + XN, Sb, lfull);

  pv_pair<<<512, 256, 0, stream>>>(Sb, Qb + 2 * XN, lfull, out);
}